// Round 6
// baseline (1055.677 us; speedup 1.0000x reference)
//
#include <hip/hip_runtime.h>

// ---------------------------------------------------------------------------
// MobileViTBlockv2 — fused-chain bf16 MFMA version.
// B=32, C=128, H=W=64, D=256, FF=512, NL=2, PH=PW=2
// p: (B, D, 4, 1024) fp32. Attention chain (v->relu*ctx->out) and FFN chain
// (f1->lrelu->f2) each fused into ONE kernel.
//
// R1: 32-col tiles + double-buffered chunk staging (occupancy fix).
// R2: next-LN stats fused into k_fused epilogue (removes 4/5 k_lnstats). BEST=780.
// R3: NT=64 A-once slab split — cold residual RMW re-missed HBM. REGRESSED.
// R4: register-held residual — VGPR spill to scratch. REGRESSED.
// R5: residual in acc2 init — epilogue WRITE still missed (fetch-on-write);
//     no savings. Lesson: NT=64 lifetime kills all end-of-block p touches.
// R6: NT=32 (R2 memory behavior: short lifetime, RMW epilogue write-hit)
//     + A-tile staged ONCE in B-frag LDS (no staging barriers, pipelined)
//     + 128-row slab split with conflict-free contiguous fragment reads
//     + LDS 25 KB -> 5 blocks/CU via __launch_bounds__(256,5).
// ---------------------------------------------------------------------------

typedef short  bh8 __attribute__((ext_vector_type(8)));   // 8 bf16 = 4 VGPR
typedef float  f4  __attribute__((ext_vector_type(4)));   // MFMA acc
typedef unsigned short us2 __attribute__((ext_vector_type(2)));
typedef unsigned short us4 __attribute__((ext_vector_type(4)));

constexpr int Bc = 32, Cc = 128, Dc = 256, FFc = 512;
constexpr int NNc = 1024, Sc = 4096;
constexpr float EPSc = 1e-5f;

enum SrcMode { S_LNF32, S_BF16 };
enum OutMode { O_STOREF32, O_FOLDBN };

__device__ __forceinline__ unsigned short f2bf(float f) {
  union { float f; unsigned int u; } v; v.f = f;
  unsigned int u = v.u + 0x7FFFu + ((v.u >> 16) & 1u);
  return (unsigned short)(u >> 16);
}

// ---- weight fp32 -> bf16 MFMA A-fragment order ----------------------------
// (m,k) -> ((kt*(M/16)+mt)*64 + lane)*8 + j ; lane=((k>>3)&3)<<4|(m&15), j=k&7
__global__ __launch_bounds__(256) void k_wconv(
    const float* __restrict__ w, unsigned short* __restrict__ dst,
    int total, int klog2)
{
  int idx = blockIdx.x * 256 + threadIdx.x;
  if (idx >= total) return;
  int K = 1 << klog2;
  int m = idx >> klog2, k = idx & (K - 1);
  int Mt = total >> klog2;
  size_t a = ((size_t)((k >> 5) * (Mt >> 4) + (m >> 4)) * 64
              + (((k >> 3) & 3) << 4) + (m & 15)) * 8 + (k & 7);
  dst[a] = f2bf(w[idx]);
}

// ---- dwconv 3x3 + BN1 + lrelu, 4 pixels/thread, bf16 patch layout ---------
__global__ __launch_bounds__(256) void k_dwconv(
    const float* __restrict__ x, const float* __restrict__ dww,
    const float* __restrict__ g, const float* __restrict__ bb,
    const float* __restrict__ mm, const float* __restrict__ vv,
    unsigned short* __restrict__ y1)
{
  int idx = blockIdx.x * 256 + threadIdx.x;   // (b,c,h,w4)
  int w4 = (idx & 15) * 4;
  int h  = (idx >> 4) & 63;
  int c  = (idx >> 10) & 127;
  int bi = idx >> 17;
  const float* xb = x + (size_t)(bi * 128 + c) * Sc;
  const float* wp = dww + c * 9;
  float acc[4] = {0.f, 0.f, 0.f, 0.f};
  #pragma unroll
  for (int kh = 0; kh < 3; ++kh) {
    int rr = h + kh - 1;
    if (rr < 0 || rr > 63) continue;
    const float* row = xb + rr * 64;
    float4 m4 = *reinterpret_cast<const float4*>(row + w4);
    float v[6];
    v[0] = (w4 > 0)  ? row[w4 - 1] : 0.f;
    v[1] = m4.x; v[2] = m4.y; v[3] = m4.z; v[4] = m4.w;
    v[5] = (w4 < 60) ? row[w4 + 4] : 0.f;
    float w0 = wp[kh * 3], w1 = wp[kh * 3 + 1], w2 = wp[kh * 3 + 2];
    #pragma unroll
    for (int o = 0; o < 4; ++o)
      acc[o] += w0 * v[o] + w1 * v[o + 1] + w2 * v[o + 2];
  }
  float sc = g[c] * rsqrtf(vv[c] + EPSc);
  float sh = bb[c] - mm[c] * sc;
  unsigned short r[4];
  #pragma unroll
  for (int o = 0; o < 4; ++o) {
    float val = acc[o] * sc + sh;
    r[o] = f2bf(val > 0.f ? val : 0.1f * val);
  }
  int ph = h & 1;
  size_t base = (size_t)(bi * 128 + c) * Sc + (h >> 1) * 32 + (w4 >> 1);
  *reinterpret_cast<us2*>(y1 + base + (ph * 2 + 0) * NNc) = (us2){r[0], r[2]};
  *reinterpret_cast<us2*>(y1 + base + (ph * 2 + 1) * NNc) = (us2){r[1], r[3]};
}

// ---- LN stats over D, optionally fused q-dot (only used once, after c1) ---
template<bool QD>
__global__ __launch_bounds__(256) void k_lnstats(
    const float* __restrict__ p, const float* __restrict__ wgq,
    float* __restrict__ mean_, float* __restrict__ rstd_, float* __restrict__ qdot)
{
  __shared__ float wg_s[256];
  int t = threadIdx.x;
  if (QD) { wg_s[t] = wgq[t]; __syncthreads(); }
  int pos = blockIdx.x * 256 + t;
  int b = pos >> 12, s = pos & 4095;
  const float* base = p + (size_t)b * Dc * Sc + s;
  float sum = 0.f, sq = 0.f, qa = 0.f;
  for (int d = 0; d < Dc; ++d) {
    float v = base[(size_t)d * Sc];
    sum += v; sq += v * v;
    if (QD) qa += v * wg_s[d];
  }
  float m   = sum * (1.f / Dc);
  float var = sq * (1.f / Dc) - m * m;
  mean_[pos] = m;
  rstd_[pos] = rsqrtf(fmaxf(var, 0.f) + EPSc);
  if (QD) qdot[pos] = qa;
}

// ---- per-layer prep: wgq = wq*g, s1 = sum(wq*g), s2 = sum(wq*b)+bq --------
__global__ void k_prep(const float* __restrict__ wq, const float* __restrict__ lng,
                       const float* __restrict__ lnb, const float* __restrict__ qb,
                       float* __restrict__ wgq, float* __restrict__ scal)
{
  int t = threadIdx.x, lane = t & 63, wv = t >> 6;
  float w = wq[t];
  float a = w * lng[t], c2 = w * lnb[t];
  wgq[t] = a;
  __shared__ float ra[4], rb[4];
  #pragma unroll
  for (int off = 32; off > 0; off >>= 1) { a += __shfl_xor(a, off); c2 += __shfl_xor(c2, off); }
  if (lane == 0) { ra[wv] = a; rb[wv] = c2; }
  __syncthreads();
  if (t == 0) {
    scal[0] = ra[0] + ra[1] + ra[2] + ra[3];
    scal[1] = rb[0] + rb[1] + rb[2] + rb[3] + qb[0];
  }
}

// ---- softmax over N from qdot/stats; emits u[n]=rs*s and U=sum(m*u) -------
__global__ __launch_bounds__(256) void k_softmax2(
    const float* __restrict__ qdot, const float* __restrict__ mean_,
    const float* __restrict__ rstd_, const float* __restrict__ scal,
    float* __restrict__ ub, float* __restrict__ Ub)
{
  int bp = blockIdx.x, b = bp >> 2, pp = bp & 3;
  int t = threadIdx.x, lane = t & 63, wv = t >> 6;
  __shared__ float r3[4], r4[4];
  float s1 = scal[0], s2 = scal[1];
  int pos0 = b * Sc + pp * NNc;
  float q[4], m_r[4], rs_r[4];
  float mx = -3.4e38f;
  #pragma unroll
  for (int i = 0; i < 4; ++i) {
    int pos = pos0 + t + i * 256;
    m_r[i] = mean_[pos]; rs_r[i] = rstd_[pos];
    q[i] = rs_r[i] * qdot[pos] - m_r[i] * rs_r[i] * s1 + s2;
    mx = fmaxf(mx, q[i]);
  }
  #pragma unroll
  for (int off = 32; off > 0; off >>= 1) mx = fmaxf(mx, __shfl_xor(mx, off));
  if (lane == 0) r3[wv] = mx;
  __syncthreads();
  mx = fmaxf(fmaxf(r3[0], r3[1]), fmaxf(r3[2], r3[3]));
  float sum = 0.f;
  #pragma unroll
  for (int i = 0; i < 4; ++i) { q[i] = __expf(q[i] - mx); sum += q[i]; }
  #pragma unroll
  for (int off = 32; off > 0; off >>= 1) sum += __shfl_xor(sum, off);
  if (lane == 0) r4[wv] = sum;
  __syncthreads();
  float inv = 1.f / (r4[0] + r4[1] + r4[2] + r4[3]);
  float pU = 0.f;
  #pragma unroll
  for (int i = 0; i < 4; ++i) {
    float un = rs_r[i] * q[i] * inv;
    ub[(size_t)bp * NNc + t + i * 256] = un;
    pU += m_r[i] * un;
  }
  #pragma unroll
  for (int off = 32; off > 0; off >>= 1) pU += __shfl_xor(pU, off);
  if (lane == 0) r3[wv] = pU;
  __syncthreads();
  if (t == 0) Ub[bp] = r3[0] + r3[1] + r3[2] + r3[3];
}

// ---- t_c = g_c*(sum_n p[c,n]*u[n] - U) + b_c ------------------------------
__global__ __launch_bounds__(256) void k_tpass(
    const float* __restrict__ p, const float* __restrict__ ub,
    const float* __restrict__ Ub, const float* __restrict__ lng,
    const float* __restrict__ lnb, float* __restrict__ tb)
{
  int cs = blockIdx.x, pp = blockIdx.y, b = blockIdx.z;
  int bp = b * 4 + pp;
  int t = threadIdx.x, lane = t & 63, wv = t >> 6;
  __shared__ float u_s[1024];
  for (int i = t; i < 1024; i += 256) u_s[i] = ub[(size_t)bp * NNc + i];
  __syncthreads();
  float U = Ub[bp];
  const float* pb = p + (size_t)b * Dc * Sc + pp * NNc;
  for (int i = 0; i < 16; ++i) {
    int c = cs * 64 + wv * 16 + i;
    const float* row = pb + (size_t)c * Sc;
    float sm = 0.f;
    #pragma unroll
    for (int j = 0; j < 16; ++j) { int n = lane + 64 * j; sm += row[n] * u_s[n]; }
    #pragma unroll
    for (int off = 32; off > 0; off >>= 1) sm += __shfl_xor(sm, off);
    if (lane == 0) tb[(size_t)bp * Dc + c] = lng[c] * (sm - U) + lnb[c];
  }
}

// ---- ctx[b,d,pp] = wk_row_d . t[b,pp,:] + bk_d ----------------------------
__global__ __launch_bounds__(256) void k_ctx2(
    const float* __restrict__ tb, const float* __restrict__ wk,
    const float* __restrict__ bk, float* __restrict__ ctxb)
{
  int b = blockIdx.x, d = threadIdx.x;
  __shared__ float ts[4][256];
  for (int i = threadIdx.x; i < 1024; i += 256) ts[i >> 8][i & 255] = tb[(size_t)b * 1024 + i];
  __syncthreads();
  const float* wrow = wk + (size_t)d * 256;
  float bkd = bk[d];
  float accp[4] = {0.f, 0.f, 0.f, 0.f};
  for (int c = 0; c < 256; c += 4) {
    float4 wv = *reinterpret_cast<const float4*>(wrow + c);
    #pragma unroll
    for (int pp = 0; pp < 4; ++pp)
      accp[pp] += wv.x * ts[pp][c] + wv.y * ts[pp][c + 1]
                + wv.z * ts[pp][c + 2] + wv.w * ts[pp][c + 3];
  }
  #pragma unroll
  for (int pp = 0; pp < 4; ++pp)
    ctxb[((size_t)(b * 256 + d)) * 4 + pp] = accp[pp] + bkd;
}

__global__ void k_bn2pre(const float* __restrict__ g, const float* __restrict__ bb,
                         const float* __restrict__ mm, const float* __restrict__ vv,
                         float* __restrict__ sc, float* __restrict__ sh)
{
  int c = threadIdx.x;
  if (c < Cc) {
    float s = g[c] * rsqrtf(vv[c] + EPSc);
    sc[c] = s;
    sh[c] = bb[c] - mm[c] * s;
  }
}

// ---------------------------------------------------------------------------
// Fused chain kernel (R6): one (b, pp, 32-col n-tile) per block, 4 waves.
// Stage: full LN(p) 256x32 bf16 A-tile in LDS (B-frag order), ONCE,
//        pipelined float2 loads, no barriers inside staging.
// For each 128-row slab s of M1:
//   phase 1: acc1 = W1[slab] @ A   (zero barriers; contiguous b128 reads)
//   act -> Frag (8 KB, B-frag order), barrier
//   phase 2: acc2 += W2[:,slab] @ Frag
// Epilogue: RMW residual (read right before write -> guaranteed write-hit)
//           + next-LN stats (mean/rstd[/qdot]).
// LDS ~25 KB -> 5 blocks/CU (launch_bounds(256,5)); W1+W2 read once/block.
// ---------------------------------------------------------------------------
template<int M1, bool ATTN, bool QDOT>
__global__ __launch_bounds__(256, 5) void k_fused(
    const float* __restrict__ p,
    const float* __restrict__ mean_, const float* __restrict__ rstd_,
    const float* __restrict__ lng, const float* __restrict__ lnb,
    const unsigned short* __restrict__ wf1, const float* __restrict__ b1,
    const float* __restrict__ ctxp,
    const unsigned short* __restrict__ wf2, const float* __restrict__ b2,
    float* __restrict__ dst,
    const float* __restrict__ wgq2,
    float* __restrict__ mean_o, float* __restrict__ rstd_o,
    float* __restrict__ qdot_o)
{
  constexpr int NT = 32;                 // n-tile columns
  constexpr int NF = 2;                  // B fragments per tile
  constexpr int SLABS = M1 / 128;        // 128-row slabs
  int t = threadIdx.x;
  int wv = t >> 6, lane = t & 63;
  int q = lane >> 4, ln16 = lane & 15;
  int nt = blockIdx.x, pp = blockIdx.y, b = blockIdx.z;
  int n0 = nt * NT;

  __shared__ unsigned int At[4096];           // 16 KB: 256k x 32n bf16, B-frag order
  __shared__ unsigned short Frag[128 * NT];   // 8 KB slab intermediate
  __shared__ float m_s[NT], rs_s[NT];
  __shared__ float ctx_s[ATTN ? 256 : 4];

  size_t pbase = (size_t)b * Dc * Sc + pp * NNc + n0;

  // staging assignment: thread -> (k-pair slot 0..15, col pair 0..15)
  int kp_s = t >> 4;             // 0..15
  int col  = (t & 15) * 2;       // 0..30
  auto kof = [&](int it) { return (it << 5) + kp_s * 2; };   // 8 iterations cover k 0..255

  // prefetch iterations 0 and 1 (independent of m_s)
  int ka = kof(0), kb = kof(1);
  float2 a0 = *reinterpret_cast<const float2*>(p + pbase + (size_t)ka * Sc + col);
  float2 a1 = *reinterpret_cast<const float2*>(p + pbase + (size_t)(ka + 1) * Sc + col);
  float2 b0 = *reinterpret_cast<const float2*>(p + pbase + (size_t)kb * Sc + col);
  float2 b1v = *reinterpret_cast<const float2*>(p + pbase + (size_t)(kb + 1) * Sc + col);

  if (t < NT) {
    int pos = b * Sc + pp * NNc + n0 + t;
    m_s[t]  = mean_[pos];
    rs_s[t] = rstd_[pos];
  }
  if (ATTN) ctx_s[t] = ctxp[(size_t)(b * Dc + t) * 4 + pp];
  __syncthreads();   // m_s/rs_s/ctx_s ready

  float ms0 = m_s[col], rs0 = rs_s[col];
  float ms1 = m_s[col + 1], rs1 = rs_s[col + 1];

  // B-frag-order write: (k,c) -> word ((k>>5)*2+(c>>4))*256 + (((k>>3)&3)*16+(c&15))*4 + ((k&7)>>1)
  auto wrA = [&](int k0, int cx, unsigned int pk) {
    At[(((k0 >> 5) * 2 + (cx >> 4)) << 8) + ((((k0 >> 3) & 3) * 16 + (cx & 15)) << 2)
       + ((k0 & 7) >> 1)] = pk;
  };

  // ---- stage full A-tile (8 iterations, 2-deep pipeline, no barriers) ----
  #pragma unroll
  for (int it = 0; it < 8; it += 2) {
    {
      int k0 = kof(it);
      float g0 = lng[k0], g1 = lng[k0 + 1];
      float h0 = lnb[k0], h1 = lnb[k0 + 1];
      float v00 = (a0.x - ms0) * rs0 * g0 + h0;
      float v01 = (a0.y - ms1) * rs1 * g0 + h0;
      float v10 = (a1.x - ms0) * rs0 * g1 + h1;
      float v11 = (a1.y - ms1) * rs1 * g1 + h1;
      if (it + 2 < 8) {
        int kn = kof(it + 2);
        a0 = *reinterpret_cast<const float2*>(p + pbase + (size_t)kn * Sc + col);
        a1 = *reinterpret_cast<const float2*>(p + pbase + (size_t)(kn + 1) * Sc + col);
      }
      wrA(k0, col,     (unsigned int)f2bf(v00) | ((unsigned int)f2bf(v10) << 16));
      wrA(k0, col + 1, (unsigned int)f2bf(v01) | ((unsigned int)f2bf(v11) << 16));
    }
    {
      int k0 = kof(it + 1);
      float g0 = lng[k0], g1 = lng[k0 + 1];
      float h0 = lnb[k0], h1 = lnb[k0 + 1];
      float v00 = (b0.x - ms0) * rs0 * g0 + h0;
      float v01 = (b0.y - ms1) * rs1 * g0 + h0;
      float v10 = (b1v.x - ms0) * rs0 * g1 + h1;
      float v11 = (b1v.y - ms1) * rs1 * g1 + h1;
      if (it + 3 < 8) {
        int kn = kof(it + 3);
        b0  = *reinterpret_cast<const float2*>(p + pbase + (size_t)kn * Sc + col);
        b1v = *reinterpret_cast<const float2*>(p + pbase + (size_t)(kn + 1) * Sc + col);
      }
      wrA(k0, col,     (unsigned int)f2bf(v00) | ((unsigned int)f2bf(v10) << 16));
      wrA(k0, col + 1, (unsigned int)f2bf(v01) | ((unsigned int)f2bf(v11) << 16));
    }
  }
  __syncthreads();   // A-tile complete

  const unsigned short* Ats = (const unsigned short*)At;

  f4 acc2[4][NF];
  #pragma unroll
  for (int i = 0; i < 4; ++i)
    #pragma unroll
    for (int j = 0; j < NF; ++j) acc2[i][j] = (f4){0.f, 0.f, 0.f, 0.f};

  for (int s = 0; s < SLABS; ++s) {
    // ---- phase 1: this wave's 32 rows of slab s (no barriers) ----
    f4 acc1[2][NF];
    #pragma unroll
    for (int i = 0; i < 2; ++i)
      #pragma unroll
      for (int j = 0; j < NF; ++j) acc1[i][j] = (f4){0.f, 0.f, 0.f, 0.f};

    for (int kc = 0; kc < 256; kc += 32) {
      bh8 aw[2];
      #pragma unroll
      for (int tm = 0; tm < 2; ++tm)
        aw[tm] = *(const bh8*)(wf1 + ((size_t)((kc >> 5) * (M1 >> 4) + s * 8 + wv * 2 + tm) * 64 + lane) * 8);
      #pragma unroll
      for (int tn = 0; tn < NF; ++tn) {
        bh8 bwf = *(const bh8*)(Ats + ((kc >> 5) * 2 + tn) * 512 + lane * 8);
        #pragma unroll
        for (int tm = 0; tm < 2; ++tm)
          acc1[tm][tn] = __builtin_amdgcn_mfma_f32_16x16x32_bf16(aw[tm], bwf, acc1[tm][tn], 0, 0, 0);
      }
    }

    __syncthreads();   // previous slab's phase-2 reads of Frag are done

    // ---- slab epilogue: act + write Frag (B-frag order, slab-local k) ----
    #pragma unroll
    for (int tm = 0; tm < 2; ++tm) {
      int row0l = wv * 32 + tm * 16 + q * 4;
      int row0g = s * 128 + row0l;
      float bia[4], cxv[4];
      #pragma unroll
      for (int r = 0; r < 4; ++r) {
        bia[r] = b1[row0g + r];
        if (ATTN) cxv[r] = ctx_s[row0g + r];
      }
      int kt2 = row0l >> 5;
      int sub = (row0l >> 3) & 3;
      int jo  = row0l & 7;
      #pragma unroll
      for (int tn = 0; tn < NF; ++tn) {
        int cl = tn * 16 + ln16;
        us4 pk;
        #pragma unroll
        for (int r = 0; r < 4; ++r) {
          float v = acc1[tm][tn][r] + bia[r];
          if (ATTN) v = fmaxf(v, 0.f) * cxv[r];
          else      v = v > 0.f ? v : 0.1f * v;
          pk[r] = f2bf(v);
        }
        *reinterpret_cast<us4*>(Frag + (((kt2 * 2 + (cl >> 4)) * 64 + ((sub << 4) | (cl & 15))) * 8 + jo)) = pk;
      }
    }
    __syncthreads();   // Frag ready

    // ---- phase 2 partial: acc2 += W2[:, slab] @ Frag ----
    for (int kc2 = 0; kc2 < 4; ++kc2) {
      bh8 aw2[4];
      #pragma unroll
      for (int tm = 0; tm < 4; ++tm)
        aw2[tm] = *(const bh8*)(wf2 + ((size_t)((s * 4 + kc2) * 16 + wv * 4 + tm) * 64 + lane) * 8);
      #pragma unroll
      for (int tn = 0; tn < NF; ++tn) {
        bh8 bwf = *(const bh8*)(Frag + (kc2 * 2 + tn) * 512 + lane * 8);
        #pragma unroll
        for (int tm = 0; tm < 4; ++tm)
          acc2[tm][tn] = __builtin_amdgcn_mfma_f32_16x16x32_bf16(aw2[tm], bwf, acc2[tm][tn], 0, 0, 0);
      }
    }
  }

  // ---- final epilogue: residual RMW (read right before write) + stats ----
  float s1[NF], s2[NF], s3[NF];
  #pragma unroll
  for (int tn = 0; tn < NF; ++tn) { s1[tn] = 0.f; s2[tn] = 0.f; s3[tn] = 0.f; }
  #pragma unroll
  for (int tm = 0; tm < 4; ++tm) {
    #pragma unroll
    for (int r = 0; r < 4; ++r) {
      int row = wv * 64 + tm * 16 + q * 4 + r;
      float bv = b2[row];
      float wqr = QDOT ? wgq2[row] : 0.f;
      #pragma unroll
      for (int tn = 0; tn < NF; ++tn) {
        int cx = n0 + tn * 16 + ln16;
        size_t da = (size_t)(b * Dc + row) * Sc + pp * NNc + cx;
        float v = dst[da] + acc2[tm][tn][r] + bv;
        dst[da] = v;
        s1[tn] += v; s2[tn] += v * v;
        if (QDOT) s3[tn] += v * wqr;
      }
    }
  }
  // reduce over q (lane bits 4,5): each wave covers 64 rows of the column
  #pragma unroll
  for (int tn = 0; tn < NF; ++tn) {
    s1[tn] += __shfl_xor(s1[tn], 16); s1[tn] += __shfl_xor(s1[tn], 32);
    s2[tn] += __shfl_xor(s2[tn], 16); s2[tn] += __shfl_xor(s2[tn], 32);
    if (QDOT) { s3[tn] += __shfl_xor(s3[tn], 16); s3[tn] += __shfl_xor(s3[tn], 32); }
  }
  __syncthreads();               // all waves done with Frag
  float* fr = (float*)Frag;      // reuse: [wv][3][NT]
  if (q == 0) {
    #pragma unroll
    for (int tn = 0; tn < NF; ++tn) {
      int cx = tn * 16 + ln16;
      fr[(wv * 3 + 0) * NT + cx] = s1[tn];
      fr[(wv * 3 + 1) * NT + cx] = s2[tn];
      fr[(wv * 3 + 2) * NT + cx] = s3[tn];
    }
  }
  __syncthreads();
  if (t < NT) {
    float a1s = 0.f, a2s = 0.f, a3s = 0.f;
    #pragma unroll
    for (int w2 = 0; w2 < 4; ++w2) {
      a1s += fr[(w2 * 3 + 0) * NT + t];
      a2s += fr[(w2 * 3 + 1) * NT + t];
      a3s += fr[(w2 * 3 + 2) * NT + t];
    }
    int pos = b * Sc + pp * NNc + n0 + t;
    float mn  = a1s * (1.f / 256.f);
    float var = a2s * (1.f / 256.f) - mn * mn;
    mean_o[pos] = mn;
    rstd_o[pos] = rsqrtf(fmaxf(var, 0.f) + EPSc);
    if (QDOT) qdot_o[pos] = a3s;
  }
}

// ---------------------------------------------------------------------------
// Standalone MFMA GEMM (used for c1 and proj).
// ---------------------------------------------------------------------------
template<int KTOT, int MTOT, int SRCCH, int SSTR, bool SPP,
         SrcMode SM, OutMode OM>
__global__ __launch_bounds__(256) void k_mm(
    const void* __restrict__ src,
    const float* __restrict__ mean_, const float* __restrict__ rstd_,
    const float* __restrict__ lng, const float* __restrict__ lnb,
    const unsigned short* __restrict__ wf, const float* __restrict__ bias,
    const float* __restrict__ bnsc, const float* __restrict__ bnsh,
    void* __restrict__ dst)
{
  int t = threadIdx.x;
  int wv = t >> 6, lane = t & 63;
  int wm = wv & 1, wn = wv >> 1;
  int q = lane >> 4, ln16 = lane & 15;
  int nb = blockIdx.x, b = blockIdx.z;
  int pp = blockIdx.y & 3, mb = blockIdx.y >> 2;
  int n0  = nb * 128;
  int MB0 = mb * 128;

  __shared__ unsigned int Alds[128 * 20];
  __shared__ float m_s[128], rs_s[128];

  if (SM == S_LNF32 && t < 128) {
    int pos = b * Sc + pp * NNc + n0 + t;
    m_s[t]  = mean_[pos];
    rs_s[t] = rstd_[pos];
  }

  f4 acc[4][4];
  #pragma unroll
  for (int i = 0; i < 4; ++i)
    #pragma unroll
    for (int j = 0; j < 4; ++j) acc[i][j] = (f4){0.f, 0.f, 0.f, 0.f};

  size_t sbase = (size_t)b * SRCCH * SSTR + pp * NNc + n0;
  int mtb = (MB0 >> 4) + wm * 4;

  for (int kc = 0; kc < KTOT; kc += 32) {
    bh8 aw[4];
    #pragma unroll
    for (int tm = 0; tm < 4; ++tm)
      aw[tm] = *(const bh8*)(wf + ((size_t)((kc >> 5) * (MTOT >> 4) + mtb + tm) * 64 + lane) * 8);
    __syncthreads();
    #pragma unroll
    for (int it = 0; it < 8; ++it) {
      int n_l = (t & 63) + (it & 1) * 64;
      int kp  = (t >> 6) + (it >> 1) * 4;
      int k0  = kc + kp * 2;
      unsigned int pk;
      if (SM == S_LNF32) {
        const float* sp = (const float*)src;
        float a0 = sp[sbase + (size_t)k0 * SSTR + n_l];
        float a1 = sp[sbase + (size_t)(k0 + 1) * SSTR + n_l];
        float ms = m_s[n_l], rs = rs_s[n_l];
        a0 = (a0 - ms) * rs * lng[k0] + lnb[k0];
        a1 = (a1 - ms) * rs * lng[k0 + 1] + lnb[k0 + 1];
        pk = (unsigned int)f2bf(a0) | ((unsigned int)f2bf(a1) << 16);
      } else {
        const unsigned short* sp = (const unsigned short*)src;
        unsigned int u0 = sp[sbase + (size_t)k0 * SSTR + n_l];
        unsigned int u1 = sp[sbase + (size_t)(k0 + 1) * SSTR + n_l];
        pk = u0 | (u1 << 16);
      }
      Alds[n_l * 20 + kp] = pk;
    }
    __syncthreads();
    const unsigned short* al = (const unsigned short*)Alds;
    #pragma unroll
    for (int tn = 0; tn < 4; ++tn) {
      int nrow = wn * 64 + tn * 16 + ln16;
      bh8 bwf = *(const bh8*)(al + nrow * 40 + q * 8);
      #pragma unroll
      for (int tm = 0; tm < 4; ++tm)
        acc[tm][tn] = __builtin_amdgcn_mfma_f32_16x16x32_bf16(aw[tm], bwf, acc[tm][tn], 0, 0, 0);
    }
  }

  #pragma unroll
  for (int tm = 0; tm < 4; ++tm) {
    #pragma unroll
    for (int r = 0; r < 4; ++r) {
      int row = MB0 + wm * 64 + tm * 16 + q * 4 + r;
      float scv = 0.f, shv = 0.f, bv = 0.f;
      if (OM == O_FOLDBN) { scv = bnsc[row]; shv = bnsh[row]; }
      else                { bv = bias[row]; }
      #pragma unroll
      for (int tn = 0; tn < 4; ++tn) {
        int col = n0 + wn * 64 + tn * 16 + ln16;
        float v = acc[tm][tn][r];
        if (OM == O_FOLDBN) {
          int hh = 2 * (col >> 5) + (pp >> 1), ww = 2 * (col & 31) + (pp & 1);
          ((float*)dst)[((size_t)(b * Cc + row)) * Sc + hh * 64 + ww] = v * scv + shv;
        } else {
          ((float*)dst)[(size_t)(b * MTOT + row) * Sc + pp * NNc + col] = v + bv;
        }
      }
    }
  }
}

// ---------------------------------------------------------------------------
extern "C" void kernel_launch(void* const* d_in, const int* in_sizes, int n_in,
                              void* d_out, int out_size, void* d_ws, size_t ws_size,
                              hipStream_t stream)
{
  const float* x     = (const float*)d_in[0];
  const float* dw_w  = (const float*)d_in[1];
  const float* bn1_g = (const float*)d_in[2];
  const float* bn1_b = (const float*)d_in[3];
  const float* bn1_m = (const float*)d_in[4];
  const float* bn1_v = (const float*)d_in[5];
  const float* c1_w  = (const float*)d_in[6];
  const float* c1_b  = (const float*)d_in[7];
  const float* ln1_g = (const float*)d_in[8];
  const float* ln1_b = (const float*)d_in[9];
  const float* qkv_w = (const float*)d_in[10];
  const float* qkv_b = (const float*)d_in[11];
  const float* out_w = (const float*)d_in[12];
  const float* out_b = (const float*)d_in[13];
  const float* ln2_g = (const float*)d_in[14];
  const float* ln2_b = (const float*)d_in[15];
  const float* f1_w  = (const float*)d_in[16];
  const float* f1_b  = (const float*)d_in[17];
  const float* f2_w  = (const float*)d_in[18];
  const float* f2_b  = (const float*)d_in[19];
  const float* lnf_g = (const float*)d_in[20];
  const float* lnf_b = (const float*)d_in[21];
  const float* projw = (const float*)d_in[22];
  const float* bn2_g = (const float*)d_in[23];
  const float* bn2_b = (const float*)d_in[24];
  const float* bn2_m = (const float*)d_in[25];
  const float* bn2_v = (const float*)d_in[26];
  float* out = (float*)d_out;

  // ---- workspace ----
  float* ws    = (float*)d_ws;
  float* p     = ws;                                       // 33,554,432 f
  float* reg   = p + (size_t)33554432;                     // 8,388,608 f (y1 bf16)
  unsigned short* y1u = (unsigned short*)reg;
  // reg region is dead after c1 k_mm -> reuse for ping-pong stat set B
  float* mean2 = reg;                                      // 131072 f
  float* rstd2 = reg + 131072;                             // 131072 f
  float* meanb = reg   + (size_t)8388608;
  float* rstdb = meanb + 131072;
  float* qdotb = rstdb + 131072;
  float* ub    = qdotb + 131072;
  float* Ub    = ub    + 131072;                           // 128
  float* tb    = Ub    + 128;                              // 32768
  float* ctxb  = tb    + 32768;                            // 32768
  float* wgq   = ctxb  + 32768;                            // 512 (2 layers)
  float* scal  = wgq   + 512;                              // 16
  float* bnscb = scal  + 16;                               // 128
  float* bnshb = bnscb + 128;                              // 128
  unsigned short* wfb = (unsigned short*)(bnshb + 128);
  unsigned short* wf_c1   = wfb;                           // 32768
  unsigned short* wf_v0   = wfb + 32768;                   // per-l stride 393216
  unsigned short* wf_proj = wfb + 32768 + 2 * 393216;      // 32768

  // ---- weight conversion ----
  k_wconv<<<128, 256, 0, stream>>>(c1_w, wf_c1, 256 * 128, 7);
  for (int l = 0; l < 2; ++l) {
    const float* wvp = qkv_w + ((size_t)l * 513 + 257) * Dc;
    unsigned short* base = wf_v0 + (size_t)l * 393216;
    k_wconv<<<256, 256, 0, stream>>>(wvp, base, 256 * 256, 8);
    k_wconv<<<256, 256, 0, stream>>>(out_w + (size_t)l * Dc * Dc, base + 65536, 256 * 256, 8);
    k_wconv<<<512, 256, 0, stream>>>(f1_w + (size_t)l * FFc * Dc, base + 131072, 512 * 256, 8);
    k_wconv<<<512, 256, 0, stream>>>(f2_w + (size_t)l * Dc * FFc, base + 262144, 256 * 512, 9);
  }
  k_wconv<<<128, 256, 0, stream>>>(projw, wf_proj, 128 * 256, 8);

  // ---- per-layer LN1/q prep, both layers upfront ----
  for (int l = 0; l < 2; ++l)
    k_prep<<<1, 256, 0, stream>>>(qkv_w + (size_t)l * 513 * Dc,
                                  ln1_g + l * Dc, ln1_b + l * Dc,
                                  qkv_b + l * 513, wgq + l * 256, scal + l * 2);

  // ---- 1) dwconv + BN1 + lrelu -> y1 bf16 (patch layout) ----
  k_dwconv<<<16384, 256, 0, stream>>>(x, dw_w, bn1_g, bn1_b, bn1_m, bn1_v, y1u);

  // ---- 2) c1: p = W_c1 @ y1 + b ----
  k_mm<128, 256, 128, 4096, true, S_BF16, O_STOREF32>
      <<<dim3(8, 8, 32), 256, 0, stream>>>(
      y1u, nullptr, nullptr, nullptr, nullptr, wf_c1, c1_b, nullptr, nullptr, p);

  // ln1 stats + qdot for layer 0 (the only standalone stats pass left)
  k_lnstats<true><<<512, 256, 0, stream>>>(p, wgq, meanb, rstdb, qdotb);

  for (int l = 0; l < 2; ++l) {
    const float* g1 = ln1_g + l * Dc; const float* b1 = ln1_b + l * Dc;
    const float* g2 = ln2_g + l * Dc; const float* b2 = ln2_b + l * Dc;
    const float* wk = qkv_w + ((size_t)l * 513 + 1) * Dc;
    const float* bk = qkv_b + l * 513 + 1;
    const float* bvv = qkv_b + l * 513 + 257;
    unsigned short* wbase = wf_v0 + (size_t)l * 393216;

    k_softmax2<<<128, 256, 0, stream>>>(qdotb, meanb, rstdb, scal + l * 2, ub, Ub);
    k_tpass<<<dim3(4, 4, 32), 256, 0, stream>>>(p, ub, Ub, g1, b1, tb);
    k_ctx2<<<32, 256, 0, stream>>>(tb, wk, bk, ctxb);

    // fused attention: p += W_out @ (relu(W_v @ LN1(p) + b_v) * ctx) + b_out
    // epilogue -> LN2 stats into set B
    k_fused<256, true, false><<<dim3(32, 4, 32), 256, 0, stream>>>(
        p, meanb, rstdb, g1, b1, wbase, bvv, ctxb,
        wbase + 65536, out_b + l * Dc, p,
        nullptr, mean2, rstd2, nullptr);

    // fused FFN: p += W2 @ lrelu(W1 @ LN2(p) + b1) + b2
    // epilogue -> next LN1 (l=0: +qdot for layer 1) or LNf (l=1) into set A
    if (l == 0) {
      k_fused<512, false, true><<<dim3(32, 4, 32), 256, 0, stream>>>(
          p, mean2, rstd2, g2, b2, wbase + 131072, f1_b + l * FFc, nullptr,
          wbase + 262144, f2_b + l * Dc, p,
          wgq + 256, meanb, rstdb, qdotb);
    } else {
      k_fused<512, false, false><<<dim3(32, 4, 32), 256, 0, stream>>>(
          p, mean2, rstd2, g2, b2, wbase + 131072, f1_b + l * FFc, nullptr,
          wbase + 262144, f2_b + l * Dc, p,
          nullptr, meanb, rstdb, nullptr);
    }
  }

  k_bn2pre<<<1, 128, 0, stream>>>(bn2_g, bn2_b, bn2_m, bn2_v, bnscb, bnshb);
  // out = BN2(proj @ LNf(p)) fused with fold; LNf stats came from last FFN epilogue
  k_mm<256, 128, 256, 4096, true, S_LNF32, O_FOLDBN>
      <<<dim3(8, 4, 32), 256, 0, stream>>>(
      p, meanb, rstdb, lnf_g, lnf_b, wf_proj, nullptr, bnscb, bnshb, out);
}

// Round 7
// 853.186 us; speedup vs baseline: 1.2373x; 1.2373x over previous
//
#include <hip/hip_runtime.h>

// ---------------------------------------------------------------------------
// MobileViTBlockv2 — fused-chain bf16 MFMA version.
// B=32, C=128, H=W=64, D=256, FF=512, NL=2, PH=PW=2
// p: (B, D, 4, 1024) fp32. Attention chain (v->relu*ctx->out) and FFN chain
// (f1->lrelu->f2) each fused into ONE kernel.
//
// R1: 32-col tiles + double-buffered chunk staging (occupancy fix).
// R2: next-LN stats fused into k_fused epilogue (removes 4/5 k_lnstats). 780us.
// R3: NT=64 A-once slab split — cold residual RMW re-missed HBM. REGRESSED.
// R4: register-held residual — VGPR spill to scratch. REGRESSED.
// R5: residual in acc2 init — epilogue WRITE still missed (fetch-on-write).
// R6: NT=32 A-once + slab split + conflict-free reads, but launch_bounds(256,5)
//     clamped VGPR to 48 -> acc arrays spilled, 330 MB scratch traffic. The
//     STRUCTURE worked (occupancy 50%, conflicts down); the bound broke it.
// R7: R6 with launch_bounds(256,4): VGPR cap 128 >= ~90 needed -> no spill.
//     HW can still run 5 blocks/CU if actual VGPR allows (bound is a floor).
// ---------------------------------------------------------------------------

typedef short  bh8 __attribute__((ext_vector_type(8)));   // 8 bf16 = 4 VGPR
typedef float  f4  __attribute__((ext_vector_type(4)));   // MFMA acc
typedef unsigned short us2 __attribute__((ext_vector_type(2)));
typedef unsigned short us4 __attribute__((ext_vector_type(4)));

constexpr int Bc = 32, Cc = 128, Dc = 256, FFc = 512;
constexpr int NNc = 1024, Sc = 4096;
constexpr float EPSc = 1e-5f;

enum SrcMode { S_LNF32, S_BF16 };
enum OutMode { O_STOREF32, O_FOLDBN };

__device__ __forceinline__ unsigned short f2bf(float f) {
  union { float f; unsigned int u; } v; v.f = f;
  unsigned int u = v.u + 0x7FFFu + ((v.u >> 16) & 1u);
  return (unsigned short)(u >> 16);
}

// ---- weight fp32 -> bf16 MFMA A-fragment order ----------------------------
// (m,k) -> ((kt*(M/16)+mt)*64 + lane)*8 + j ; lane=((k>>3)&3)<<4|(m&15), j=k&7
__global__ __launch_bounds__(256) void k_wconv(
    const float* __restrict__ w, unsigned short* __restrict__ dst,
    int total, int klog2)
{
  int idx = blockIdx.x * 256 + threadIdx.x;
  if (idx >= total) return;
  int K = 1 << klog2;
  int m = idx >> klog2, k = idx & (K - 1);
  int Mt = total >> klog2;
  size_t a = ((size_t)((k >> 5) * (Mt >> 4) + (m >> 4)) * 64
              + (((k >> 3) & 3) << 4) + (m & 15)) * 8 + (k & 7);
  dst[a] = f2bf(w[idx]);
}

// ---- dwconv 3x3 + BN1 + lrelu, 4 pixels/thread, bf16 patch layout ---------
__global__ __launch_bounds__(256) void k_dwconv(
    const float* __restrict__ x, const float* __restrict__ dww,
    const float* __restrict__ g, const float* __restrict__ bb,
    const float* __restrict__ mm, const float* __restrict__ vv,
    unsigned short* __restrict__ y1)
{
  int idx = blockIdx.x * 256 + threadIdx.x;   // (b,c,h,w4)
  int w4 = (idx & 15) * 4;
  int h  = (idx >> 4) & 63;
  int c  = (idx >> 10) & 127;
  int bi = idx >> 17;
  const float* xb = x + (size_t)(bi * 128 + c) * Sc;
  const float* wp = dww + c * 9;
  float acc[4] = {0.f, 0.f, 0.f, 0.f};
  #pragma unroll
  for (int kh = 0; kh < 3; ++kh) {
    int rr = h + kh - 1;
    if (rr < 0 || rr > 63) continue;
    const float* row = xb + rr * 64;
    float4 m4 = *reinterpret_cast<const float4*>(row + w4);
    float v[6];
    v[0] = (w4 > 0)  ? row[w4 - 1] : 0.f;
    v[1] = m4.x; v[2] = m4.y; v[3] = m4.z; v[4] = m4.w;
    v[5] = (w4 < 60) ? row[w4 + 4] : 0.f;
    float w0 = wp[kh * 3], w1 = wp[kh * 3 + 1], w2 = wp[kh * 3 + 2];
    #pragma unroll
    for (int o = 0; o < 4; ++o)
      acc[o] += w0 * v[o] + w1 * v[o + 1] + w2 * v[o + 2];
  }
  float sc = g[c] * rsqrtf(vv[c] + EPSc);
  float sh = bb[c] - mm[c] * sc;
  unsigned short r[4];
  #pragma unroll
  for (int o = 0; o < 4; ++o) {
    float val = acc[o] * sc + sh;
    r[o] = f2bf(val > 0.f ? val : 0.1f * val);
  }
  int ph = h & 1;
  size_t base = (size_t)(bi * 128 + c) * Sc + (h >> 1) * 32 + (w4 >> 1);
  *reinterpret_cast<us2*>(y1 + base + (ph * 2 + 0) * NNc) = (us2){r[0], r[2]};
  *reinterpret_cast<us2*>(y1 + base + (ph * 2 + 1) * NNc) = (us2){r[1], r[3]};
}

// ---- LN stats over D, optionally fused q-dot (only used once, after c1) ---
template<bool QD>
__global__ __launch_bounds__(256) void k_lnstats(
    const float* __restrict__ p, const float* __restrict__ wgq,
    float* __restrict__ mean_, float* __restrict__ rstd_, float* __restrict__ qdot)
{
  __shared__ float wg_s[256];
  int t = threadIdx.x;
  if (QD) { wg_s[t] = wgq[t]; __syncthreads(); }
  int pos = blockIdx.x * 256 + t;
  int b = pos >> 12, s = pos & 4095;
  const float* base = p + (size_t)b * Dc * Sc + s;
  float sum = 0.f, sq = 0.f, qa = 0.f;
  for (int d = 0; d < Dc; ++d) {
    float v = base[(size_t)d * Sc];
    sum += v; sq += v * v;
    if (QD) qa += v * wg_s[d];
  }
  float m   = sum * (1.f / Dc);
  float var = sq * (1.f / Dc) - m * m;
  mean_[pos] = m;
  rstd_[pos] = rsqrtf(fmaxf(var, 0.f) + EPSc);
  if (QD) qdot[pos] = qa;
}

// ---- per-layer prep: wgq = wq*g, s1 = sum(wq*g), s2 = sum(wq*b)+bq --------
__global__ void k_prep(const float* __restrict__ wq, const float* __restrict__ lng,
                       const float* __restrict__ lnb, const float* __restrict__ qb,
                       float* __restrict__ wgq, float* __restrict__ scal)
{
  int t = threadIdx.x, lane = t & 63, wv = t >> 6;
  float w = wq[t];
  float a = w * lng[t], c2 = w * lnb[t];
  wgq[t] = a;
  __shared__ float ra[4], rb[4];
  #pragma unroll
  for (int off = 32; off > 0; off >>= 1) { a += __shfl_xor(a, off); c2 += __shfl_xor(c2, off); }
  if (lane == 0) { ra[wv] = a; rb[wv] = c2; }
  __syncthreads();
  if (t == 0) {
    scal[0] = ra[0] + ra[1] + ra[2] + ra[3];
    scal[1] = rb[0] + rb[1] + rb[2] + rb[3] + qb[0];
  }
}

// ---- softmax over N from qdot/stats; emits u[n]=rs*s and U=sum(m*u) -------
__global__ __launch_bounds__(256) void k_softmax2(
    const float* __restrict__ qdot, const float* __restrict__ mean_,
    const float* __restrict__ rstd_, const float* __restrict__ scal,
    float* __restrict__ ub, float* __restrict__ Ub)
{
  int bp = blockIdx.x, b = bp >> 2, pp = bp & 3;
  int t = threadIdx.x, lane = t & 63, wv = t >> 6;
  __shared__ float r3[4], r4[4];
  float s1 = scal[0], s2 = scal[1];
  int pos0 = b * Sc + pp * NNc;
  float q[4], m_r[4], rs_r[4];
  float mx = -3.4e38f;
  #pragma unroll
  for (int i = 0; i < 4; ++i) {
    int pos = pos0 + t + i * 256;
    m_r[i] = mean_[pos]; rs_r[i] = rstd_[pos];
    q[i] = rs_r[i] * qdot[pos] - m_r[i] * rs_r[i] * s1 + s2;
    mx = fmaxf(mx, q[i]);
  }
  #pragma unroll
  for (int off = 32; off > 0; off >>= 1) mx = fmaxf(mx, __shfl_xor(mx, off));
  if (lane == 0) r3[wv] = mx;
  __syncthreads();
  mx = fmaxf(fmaxf(r3[0], r3[1]), fmaxf(r3[2], r3[3]));
  float sum = 0.f;
  #pragma unroll
  for (int i = 0; i < 4; ++i) { q[i] = __expf(q[i] - mx); sum += q[i]; }
  #pragma unroll
  for (int off = 32; off > 0; off >>= 1) sum += __shfl_xor(sum, off);
  if (lane == 0) r4[wv] = sum;
  __syncthreads();
  float inv = 1.f / (r4[0] + r4[1] + r4[2] + r4[3]);
  float pU = 0.f;
  #pragma unroll
  for (int i = 0; i < 4; ++i) {
    float un = rs_r[i] * q[i] * inv;
    ub[(size_t)bp * NNc + t + i * 256] = un;
    pU += m_r[i] * un;
  }
  #pragma unroll
  for (int off = 32; off > 0; off >>= 1) pU += __shfl_xor(pU, off);
  if (lane == 0) r3[wv] = pU;
  __syncthreads();
  if (t == 0) Ub[bp] = r3[0] + r3[1] + r3[2] + r3[3];
}

// ---- t_c = g_c*(sum_n p[c,n]*u[n] - U) + b_c ------------------------------
__global__ __launch_bounds__(256) void k_tpass(
    const float* __restrict__ p, const float* __restrict__ ub,
    const float* __restrict__ Ub, const float* __restrict__ lng,
    const float* __restrict__ lnb, float* __restrict__ tb)
{
  int cs = blockIdx.x, pp = blockIdx.y, b = blockIdx.z;
  int bp = b * 4 + pp;
  int t = threadIdx.x, lane = t & 63, wv = t >> 6;
  __shared__ float u_s[1024];
  for (int i = t; i < 1024; i += 256) u_s[i] = ub[(size_t)bp * NNc + i];
  __syncthreads();
  float U = Ub[bp];
  const float* pb = p + (size_t)b * Dc * Sc + pp * NNc;
  for (int i = 0; i < 16; ++i) {
    int c = cs * 64 + wv * 16 + i;
    const float* row = pb + (size_t)c * Sc;
    float sm = 0.f;
    #pragma unroll
    for (int j = 0; j < 16; ++j) { int n = lane + 64 * j; sm += row[n] * u_s[n]; }
    #pragma unroll
    for (int off = 32; off > 0; off >>= 1) sm += __shfl_xor(sm, off);
    if (lane == 0) tb[(size_t)bp * Dc + c] = lng[c] * (sm - U) + lnb[c];
  }
}

// ---- ctx[b,d,pp] = wk_row_d . t[b,pp,:] + bk_d ----------------------------
__global__ __launch_bounds__(256) void k_ctx2(
    const float* __restrict__ tb, const float* __restrict__ wk,
    const float* __restrict__ bk, float* __restrict__ ctxb)
{
  int b = blockIdx.x, d = threadIdx.x;
  __shared__ float ts[4][256];
  for (int i = threadIdx.x; i < 1024; i += 256) ts[i >> 8][i & 255] = tb[(size_t)b * 1024 + i];
  __syncthreads();
  const float* wrow = wk + (size_t)d * 256;
  float bkd = bk[d];
  float accp[4] = {0.f, 0.f, 0.f, 0.f};
  for (int c = 0; c < 256; c += 4) {
    float4 wv = *reinterpret_cast<const float4*>(wrow + c);
    #pragma unroll
    for (int pp = 0; pp < 4; ++pp)
      accp[pp] += wv.x * ts[pp][c] + wv.y * ts[pp][c + 1]
                + wv.z * ts[pp][c + 2] + wv.w * ts[pp][c + 3];
  }
  #pragma unroll
  for (int pp = 0; pp < 4; ++pp)
    ctxb[((size_t)(b * 256 + d)) * 4 + pp] = accp[pp] + bkd;
}

__global__ void k_bn2pre(const float* __restrict__ g, const float* __restrict__ bb,
                         const float* __restrict__ mm, const float* __restrict__ vv,
                         float* __restrict__ sc, float* __restrict__ sh)
{
  int c = threadIdx.x;
  if (c < Cc) {
    float s = g[c] * rsqrtf(vv[c] + EPSc);
    sc[c] = s;
    sh[c] = bb[c] - mm[c] * s;
  }
}

// ---------------------------------------------------------------------------
// Fused chain kernel (R7 = R6 structure, safe launch bounds):
// one (b, pp, 32-col n-tile) per block, 4 waves.
// Stage: full LN(p) 256x32 bf16 A-tile in LDS (B-frag order), ONCE,
//        pipelined float2 loads, no barriers inside staging.
// For each 128-row slab s of M1:
//   phase 1: acc1 = W1[slab] @ A   (zero barriers; contiguous b128 reads)
//   act -> Frag (8 KB, B-frag order), barrier
//   phase 2: acc2 += W2[:,slab] @ Frag
// Epilogue: RMW residual (read right before write -> guaranteed write-hit)
//           + next-LN stats (mean/rstd[/qdot]).
// LDS ~25 KB; launch_bounds(256,4) -> VGPR cap 128 (no spill, ~90 needed);
// HW may still schedule 5 blocks/CU if actual VGPR permits.
// ---------------------------------------------------------------------------
template<int M1, bool ATTN, bool QDOT>
__global__ __launch_bounds__(256, 4) void k_fused(
    const float* __restrict__ p,
    const float* __restrict__ mean_, const float* __restrict__ rstd_,
    const float* __restrict__ lng, const float* __restrict__ lnb,
    const unsigned short* __restrict__ wf1, const float* __restrict__ b1,
    const float* __restrict__ ctxp,
    const unsigned short* __restrict__ wf2, const float* __restrict__ b2,
    float* __restrict__ dst,
    const float* __restrict__ wgq2,
    float* __restrict__ mean_o, float* __restrict__ rstd_o,
    float* __restrict__ qdot_o)
{
  constexpr int NT = 32;                 // n-tile columns
  constexpr int NF = 2;                  // B fragments per tile
  constexpr int SLABS = M1 / 128;        // 128-row slabs
  int t = threadIdx.x;
  int wv = t >> 6, lane = t & 63;
  int q = lane >> 4, ln16 = lane & 15;
  int nt = blockIdx.x, pp = blockIdx.y, b = blockIdx.z;
  int n0 = nt * NT;

  __shared__ unsigned int At[4096];           // 16 KB: 256k x 32n bf16, B-frag order
  __shared__ unsigned short Frag[128 * NT];   // 8 KB slab intermediate
  __shared__ float m_s[NT], rs_s[NT];
  __shared__ float ctx_s[ATTN ? 256 : 4];

  size_t pbase = (size_t)b * Dc * Sc + pp * NNc + n0;

  // staging assignment: thread -> (k-pair slot 0..15, col pair 0..15)
  int kp_s = t >> 4;             // 0..15
  int col  = (t & 15) * 2;       // 0..30
  auto kof = [&](int it) { return (it << 5) + kp_s * 2; };   // 8 iterations cover k 0..255

  // prefetch iterations 0 and 1 (independent of m_s)
  int ka = kof(0), kb = kof(1);
  float2 a0 = *reinterpret_cast<const float2*>(p + pbase + (size_t)ka * Sc + col);
  float2 a1 = *reinterpret_cast<const float2*>(p + pbase + (size_t)(ka + 1) * Sc + col);
  float2 b0 = *reinterpret_cast<const float2*>(p + pbase + (size_t)kb * Sc + col);
  float2 b1v = *reinterpret_cast<const float2*>(p + pbase + (size_t)(kb + 1) * Sc + col);

  if (t < NT) {
    int pos = b * Sc + pp * NNc + n0 + t;
    m_s[t]  = mean_[pos];
    rs_s[t] = rstd_[pos];
  }
  if (ATTN) ctx_s[t] = ctxp[(size_t)(b * Dc + t) * 4 + pp];
  __syncthreads();   // m_s/rs_s/ctx_s ready

  float ms0 = m_s[col], rs0 = rs_s[col];
  float ms1 = m_s[col + 1], rs1 = rs_s[col + 1];

  // B-frag-order write: (k,c) -> word ((k>>5)*2+(c>>4))*256 + (((k>>3)&3)*16+(c&15))*4 + ((k&7)>>1)
  auto wrA = [&](int k0, int cx, unsigned int pk) {
    At[(((k0 >> 5) * 2 + (cx >> 4)) << 8) + ((((k0 >> 3) & 3) * 16 + (cx & 15)) << 2)
       + ((k0 & 7) >> 1)] = pk;
  };

  // ---- stage full A-tile (8 iterations, 2-deep pipeline, no barriers) ----
  #pragma unroll
  for (int it = 0; it < 8; it += 2) {
    {
      int k0 = kof(it);
      float g0 = lng[k0], g1 = lng[k0 + 1];
      float h0 = lnb[k0], h1 = lnb[k0 + 1];
      float v00 = (a0.x - ms0) * rs0 * g0 + h0;
      float v01 = (a0.y - ms1) * rs1 * g0 + h0;
      float v10 = (a1.x - ms0) * rs0 * g1 + h1;
      float v11 = (a1.y - ms1) * rs1 * g1 + h1;
      if (it + 2 < 8) {
        int kn = kof(it + 2);
        a0 = *reinterpret_cast<const float2*>(p + pbase + (size_t)kn * Sc + col);
        a1 = *reinterpret_cast<const float2*>(p + pbase + (size_t)(kn + 1) * Sc + col);
      }
      wrA(k0, col,     (unsigned int)f2bf(v00) | ((unsigned int)f2bf(v10) << 16));
      wrA(k0, col + 1, (unsigned int)f2bf(v01) | ((unsigned int)f2bf(v11) << 16));
    }
    {
      int k0 = kof(it + 1);
      float g0 = lng[k0], g1 = lng[k0 + 1];
      float h0 = lnb[k0], h1 = lnb[k0 + 1];
      float v00 = (b0.x - ms0) * rs0 * g0 + h0;
      float v01 = (b0.y - ms1) * rs1 * g0 + h0;
      float v10 = (b1v.x - ms0) * rs0 * g1 + h1;
      float v11 = (b1v.y - ms1) * rs1 * g1 + h1;
      if (it + 3 < 8) {
        int kn = kof(it + 3);
        b0  = *reinterpret_cast<const float2*>(p + pbase + (size_t)kn * Sc + col);
        b1v = *reinterpret_cast<const float2*>(p + pbase + (size_t)(kn + 1) * Sc + col);
      }
      wrA(k0, col,     (unsigned int)f2bf(v00) | ((unsigned int)f2bf(v10) << 16));
      wrA(k0, col + 1, (unsigned int)f2bf(v01) | ((unsigned int)f2bf(v11) << 16));
    }
  }
  __syncthreads();   // A-tile complete

  const unsigned short* Ats = (const unsigned short*)At;

  f4 acc2[4][NF];
  #pragma unroll
  for (int i = 0; i < 4; ++i)
    #pragma unroll
    for (int j = 0; j < NF; ++j) acc2[i][j] = (f4){0.f, 0.f, 0.f, 0.f};

  for (int s = 0; s < SLABS; ++s) {
    // ---- phase 1: this wave's 32 rows of slab s (no barriers) ----
    f4 acc1[2][NF];
    #pragma unroll
    for (int i = 0; i < 2; ++i)
      #pragma unroll
      for (int j = 0; j < NF; ++j) acc1[i][j] = (f4){0.f, 0.f, 0.f, 0.f};

    for (int kc = 0; kc < 256; kc += 32) {
      bh8 aw[2];
      #pragma unroll
      for (int tm = 0; tm < 2; ++tm)
        aw[tm] = *(const bh8*)(wf1 + ((size_t)((kc >> 5) * (M1 >> 4) + s * 8 + wv * 2 + tm) * 64 + lane) * 8);
      #pragma unroll
      for (int tn = 0; tn < NF; ++tn) {
        bh8 bwf = *(const bh8*)(Ats + ((kc >> 5) * 2 + tn) * 512 + lane * 8);
        #pragma unroll
        for (int tm = 0; tm < 2; ++tm)
          acc1[tm][tn] = __builtin_amdgcn_mfma_f32_16x16x32_bf16(aw[tm], bwf, acc1[tm][tn], 0, 0, 0);
      }
    }

    __syncthreads();   // previous slab's phase-2 reads of Frag are done

    // ---- slab epilogue: act + write Frag (B-frag order, slab-local k) ----
    #pragma unroll
    for (int tm = 0; tm < 2; ++tm) {
      int row0l = wv * 32 + tm * 16 + q * 4;
      int row0g = s * 128 + row0l;
      float bia[4], cxv[4];
      #pragma unroll
      for (int r = 0; r < 4; ++r) {
        bia[r] = b1[row0g + r];
        if (ATTN) cxv[r] = ctx_s[row0g + r];
      }
      int kt2 = row0l >> 5;
      int sub = (row0l >> 3) & 3;
      int jo  = row0l & 7;
      #pragma unroll
      for (int tn = 0; tn < NF; ++tn) {
        int cl = tn * 16 + ln16;
        us4 pk;
        #pragma unroll
        for (int r = 0; r < 4; ++r) {
          float v = acc1[tm][tn][r] + bia[r];
          if (ATTN) v = fmaxf(v, 0.f) * cxv[r];
          else      v = v > 0.f ? v : 0.1f * v;
          pk[r] = f2bf(v);
        }
        *reinterpret_cast<us4*>(Frag + (((kt2 * 2 + (cl >> 4)) * 64 + ((sub << 4) | (cl & 15))) * 8 + jo)) = pk;
      }
    }
    __syncthreads();   // Frag ready

    // ---- phase 2 partial: acc2 += W2[:, slab] @ Frag ----
    for (int kc2 = 0; kc2 < 4; ++kc2) {
      bh8 aw2[4];
      #pragma unroll
      for (int tm = 0; tm < 4; ++tm)
        aw2[tm] = *(const bh8*)(wf2 + ((size_t)((s * 4 + kc2) * 16 + wv * 4 + tm) * 64 + lane) * 8);
      #pragma unroll
      for (int tn = 0; tn < NF; ++tn) {
        bh8 bwf = *(const bh8*)(Frag + (kc2 * 2 + tn) * 512 + lane * 8);
        #pragma unroll
        for (int tm = 0; tm < 4; ++tm)
          acc2[tm][tn] = __builtin_amdgcn_mfma_f32_16x16x32_bf16(aw2[tm], bwf, acc2[tm][tn], 0, 0, 0);
      }
    }
  }

  // ---- final epilogue: residual RMW (read right before write) + stats ----
  float s1[NF], s2[NF], s3[NF];
  #pragma unroll
  for (int tn = 0; tn < NF; ++tn) { s1[tn] = 0.f; s2[tn] = 0.f; s3[tn] = 0.f; }
  #pragma unroll
  for (int tm = 0; tm < 4; ++tm) {
    #pragma unroll
    for (int r = 0; r < 4; ++r) {
      int row = wv * 64 + tm * 16 + q * 4 + r;
      float bv = b2[row];
      float wqr = QDOT ? wgq2[row] : 0.f;
      #pragma unroll
      for (int tn = 0; tn < NF; ++tn) {
        int cx = n0 + tn * 16 + ln16;
        size_t da = (size_t)(b * Dc + row) * Sc + pp * NNc + cx;
        float v = dst[da] + acc2[tm][tn][r] + bv;
        dst[da] = v;
        s1[tn] += v; s2[tn] += v * v;
        if (QDOT) s3[tn] += v * wqr;
      }
    }
  }
  // reduce over q (lane bits 4,5): each wave covers 64 rows of the column
  #pragma unroll
  for (int tn = 0; tn < NF; ++tn) {
    s1[tn] += __shfl_xor(s1[tn], 16); s1[tn] += __shfl_xor(s1[tn], 32);
    s2[tn] += __shfl_xor(s2[tn], 16); s2[tn] += __shfl_xor(s2[tn], 32);
    if (QDOT) { s3[tn] += __shfl_xor(s3[tn], 16); s3[tn] += __shfl_xor(s3[tn], 32); }
  }
  __syncthreads();               // all waves done with Frag
  float* fr = (float*)Frag;      // reuse: [wv][3][NT]
  if (q == 0) {
    #pragma unroll
    for (int tn = 0; tn < NF; ++tn) {
      int cx = tn * 16 + ln16;
      fr[(wv * 3 + 0) * NT + cx] = s1[tn];
      fr[(wv * 3 + 1) * NT + cx] = s2[tn];
      fr[(wv * 3 + 2) * NT + cx] = s3[tn];
    }
  }
  __syncthreads();
  if (t < NT) {
    float a1s = 0.f, a2s = 0.f, a3s = 0.f;
    #pragma unroll
    for (int w2 = 0; w2 < 4; ++w2) {
      a1s += fr[(w2 * 3 + 0) * NT + t];
      a2s += fr[(w2 * 3 + 1) * NT + t];
      a3s += fr[(w2 * 3 + 2) * NT + t];
    }
    int pos = b * Sc + pp * NNc + n0 + t;
    float mn  = a1s * (1.f / 256.f);
    float var = a2s * (1.f / 256.f) - mn * mn;
    mean_o[pos] = mn;
    rstd_o[pos] = rsqrtf(fmaxf(var, 0.f) + EPSc);
    if (QDOT) qdot_o[pos] = a3s;
  }
}

// ---------------------------------------------------------------------------
// Standalone MFMA GEMM (used for c1 and proj).
// ---------------------------------------------------------------------------
template<int KTOT, int MTOT, int SRCCH, int SSTR, bool SPP,
         SrcMode SM, OutMode OM>
__global__ __launch_bounds__(256) void k_mm(
    const void* __restrict__ src,
    const float* __restrict__ mean_, const float* __restrict__ rstd_,
    const float* __restrict__ lng, const float* __restrict__ lnb,
    const unsigned short* __restrict__ wf, const float* __restrict__ bias,
    const float* __restrict__ bnsc, const float* __restrict__ bnsh,
    void* __restrict__ dst)
{
  int t = threadIdx.x;
  int wv = t >> 6, lane = t & 63;
  int wm = wv & 1, wn = wv >> 1;
  int q = lane >> 4, ln16 = lane & 15;
  int nb = blockIdx.x, b = blockIdx.z;
  int pp = blockIdx.y & 3, mb = blockIdx.y >> 2;
  int n0  = nb * 128;
  int MB0 = mb * 128;

  __shared__ unsigned int Alds[128 * 20];
  __shared__ float m_s[128], rs_s[128];

  if (SM == S_LNF32 && t < 128) {
    int pos = b * Sc + pp * NNc + n0 + t;
    m_s[t]  = mean_[pos];
    rs_s[t] = rstd_[pos];
  }

  f4 acc[4][4];
  #pragma unroll
  for (int i = 0; i < 4; ++i)
    #pragma unroll
    for (int j = 0; j < 4; ++j) acc[i][j] = (f4){0.f, 0.f, 0.f, 0.f};

  size_t sbase = (size_t)b * SRCCH * SSTR + pp * NNc + n0;
  int mtb = (MB0 >> 4) + wm * 4;

  for (int kc = 0; kc < KTOT; kc += 32) {
    bh8 aw[4];
    #pragma unroll
    for (int tm = 0; tm < 4; ++tm)
      aw[tm] = *(const bh8*)(wf + ((size_t)((kc >> 5) * (MTOT >> 4) + mtb + tm) * 64 + lane) * 8);
    __syncthreads();
    #pragma unroll
    for (int it = 0; it < 8; ++it) {
      int n_l = (t & 63) + (it & 1) * 64;
      int kp  = (t >> 6) + (it >> 1) * 4;
      int k0  = kc + kp * 2;
      unsigned int pk;
      if (SM == S_LNF32) {
        const float* sp = (const float*)src;
        float a0 = sp[sbase + (size_t)k0 * SSTR + n_l];
        float a1 = sp[sbase + (size_t)(k0 + 1) * SSTR + n_l];
        float ms = m_s[n_l], rs = rs_s[n_l];
        a0 = (a0 - ms) * rs * lng[k0] + lnb[k0];
        a1 = (a1 - ms) * rs * lng[k0 + 1] + lnb[k0 + 1];
        pk = (unsigned int)f2bf(a0) | ((unsigned int)f2bf(a1) << 16);
      } else {
        const unsigned short* sp = (const unsigned short*)src;
        unsigned int u0 = sp[sbase + (size_t)k0 * SSTR + n_l];
        unsigned int u1 = sp[sbase + (size_t)(k0 + 1) * SSTR + n_l];
        pk = u0 | (u1 << 16);
      }
      Alds[n_l * 20 + kp] = pk;
    }
    __syncthreads();
    const unsigned short* al = (const unsigned short*)Alds;
    #pragma unroll
    for (int tn = 0; tn < 4; ++tn) {
      int nrow = wn * 64 + tn * 16 + ln16;
      bh8 bwf = *(const bh8*)(al + nrow * 40 + q * 8);
      #pragma unroll
      for (int tm = 0; tm < 4; ++tm)
        acc[tm][tn] = __builtin_amdgcn_mfma_f32_16x16x32_bf16(aw[tm], bwf, acc[tm][tn], 0, 0, 0);
    }
  }

  #pragma unroll
  for (int tm = 0; tm < 4; ++tm) {
    #pragma unroll
    for (int r = 0; r < 4; ++r) {
      int row = MB0 + wm * 64 + tm * 16 + q * 4 + r;
      float scv = 0.f, shv = 0.f, bv = 0.f;
      if (OM == O_FOLDBN) { scv = bnsc[row]; shv = bnsh[row]; }
      else                { bv = bias[row]; }
      #pragma unroll
      for (int tn = 0; tn < 4; ++tn) {
        int col = n0 + wn * 64 + tn * 16 + ln16;
        float v = acc[tm][tn][r];
        if (OM == O_FOLDBN) {
          int hh = 2 * (col >> 5) + (pp >> 1), ww = 2 * (col & 31) + (pp & 1);
          ((float*)dst)[((size_t)(b * Cc + row)) * Sc + hh * 64 + ww] = v * scv + shv;
        } else {
          ((float*)dst)[(size_t)(b * MTOT + row) * Sc + pp * NNc + col] = v + bv;
        }
      }
    }
  }
}

// ---------------------------------------------------------------------------
extern "C" void kernel_launch(void* const* d_in, const int* in_sizes, int n_in,
                              void* d_out, int out_size, void* d_ws, size_t ws_size,
                              hipStream_t stream)
{
  const float* x     = (const float*)d_in[0];
  const float* dw_w  = (const float*)d_in[1];
  const float* bn1_g = (const float*)d_in[2];
  const float* bn1_b = (const float*)d_in[3];
  const float* bn1_m = (const float*)d_in[4];
  const float* bn1_v = (const float*)d_in[5];
  const float* c1_w  = (const float*)d_in[6];
  const float* c1_b  = (const float*)d_in[7];
  const float* ln1_g = (const float*)d_in[8];
  const float* ln1_b = (const float*)d_in[9];
  const float* qkv_w = (const float*)d_in[10];
  const float* qkv_b = (const float*)d_in[11];
  const float* out_w = (const float*)d_in[12];
  const float* out_b = (const float*)d_in[13];
  const float* ln2_g = (const float*)d_in[14];
  const float* ln2_b = (const float*)d_in[15];
  const float* f1_w  = (const float*)d_in[16];
  const float* f1_b  = (const float*)d_in[17];
  const float* f2_w  = (const float*)d_in[18];
  const float* f2_b  = (const float*)d_in[19];
  const float* lnf_g = (const float*)d_in[20];
  const float* lnf_b = (const float*)d_in[21];
  const float* projw = (const float*)d_in[22];
  const float* bn2_g = (const float*)d_in[23];
  const float* bn2_b = (const float*)d_in[24];
  const float* bn2_m = (const float*)d_in[25];
  const float* bn2_v = (const float*)d_in[26];
  float* out = (float*)d_out;

  // ---- workspace ----
  float* ws    = (float*)d_ws;
  float* p     = ws;                                       // 33,554,432 f
  float* reg   = p + (size_t)33554432;                     // 8,388,608 f (y1 bf16)
  unsigned short* y1u = (unsigned short*)reg;
  // reg region is dead after c1 k_mm -> reuse for ping-pong stat set B
  float* mean2 = reg;                                      // 131072 f
  float* rstd2 = reg + 131072;                             // 131072 f
  float* meanb = reg   + (size_t)8388608;
  float* rstdb = meanb + 131072;
  float* qdotb = rstdb + 131072;
  float* ub    = qdotb + 131072;
  float* Ub    = ub    + 131072;                           // 128
  float* tb    = Ub    + 128;                              // 32768
  float* ctxb  = tb    + 32768;                            // 32768
  float* wgq   = ctxb  + 32768;                            // 512 (2 layers)
  float* scal  = wgq   + 512;                              // 16
  float* bnscb = scal  + 16;                               // 128
  float* bnshb = bnscb + 128;                              // 128
  unsigned short* wfb = (unsigned short*)(bnshb + 128);
  unsigned short* wf_c1   = wfb;                           // 32768
  unsigned short* wf_v0   = wfb + 32768;                   // per-l stride 393216
  unsigned short* wf_proj = wfb + 32768 + 2 * 393216;      // 32768

  // ---- weight conversion ----
  k_wconv<<<128, 256, 0, stream>>>(c1_w, wf_c1, 256 * 128, 7);
  for (int l = 0; l < 2; ++l) {
    const float* wvp = qkv_w + ((size_t)l * 513 + 257) * Dc;
    unsigned short* base = wf_v0 + (size_t)l * 393216;
    k_wconv<<<256, 256, 0, stream>>>(wvp, base, 256 * 256, 8);
    k_wconv<<<256, 256, 0, stream>>>(out_w + (size_t)l * Dc * Dc, base + 65536, 256 * 256, 8);
    k_wconv<<<512, 256, 0, stream>>>(f1_w + (size_t)l * FFc * Dc, base + 131072, 512 * 256, 8);
    k_wconv<<<512, 256, 0, stream>>>(f2_w + (size_t)l * Dc * FFc, base + 262144, 256 * 512, 9);
  }
  k_wconv<<<128, 256, 0, stream>>>(projw, wf_proj, 128 * 256, 8);

  // ---- per-layer LN1/q prep, both layers upfront ----
  for (int l = 0; l < 2; ++l)
    k_prep<<<1, 256, 0, stream>>>(qkv_w + (size_t)l * 513 * Dc,
                                  ln1_g + l * Dc, ln1_b + l * Dc,
                                  qkv_b + l * 513, wgq + l * 256, scal + l * 2);

  // ---- 1) dwconv + BN1 + lrelu -> y1 bf16 (patch layout) ----
  k_dwconv<<<16384, 256, 0, stream>>>(x, dw_w, bn1_g, bn1_b, bn1_m, bn1_v, y1u);

  // ---- 2) c1: p = W_c1 @ y1 + b ----
  k_mm<128, 256, 128, 4096, true, S_BF16, O_STOREF32>
      <<<dim3(8, 8, 32), 256, 0, stream>>>(
      y1u, nullptr, nullptr, nullptr, nullptr, wf_c1, c1_b, nullptr, nullptr, p);

  // ln1 stats + qdot for layer 0 (the only standalone stats pass left)
  k_lnstats<true><<<512, 256, 0, stream>>>(p, wgq, meanb, rstdb, qdotb);

  for (int l = 0; l < 2; ++l) {
    const float* g1 = ln1_g + l * Dc; const float* b1 = ln1_b + l * Dc;
    const float* g2 = ln2_g + l * Dc; const float* b2 = ln2_b + l * Dc;
    const float* wk = qkv_w + ((size_t)l * 513 + 1) * Dc;
    const float* bk = qkv_b + l * 513 + 1;
    const float* bvv = qkv_b + l * 513 + 257;
    unsigned short* wbase = wf_v0 + (size_t)l * 393216;

    k_softmax2<<<128, 256, 0, stream>>>(qdotb, meanb, rstdb, scal + l * 2, ub, Ub);
    k_tpass<<<dim3(4, 4, 32), 256, 0, stream>>>(p, ub, Ub, g1, b1, tb);
    k_ctx2<<<32, 256, 0, stream>>>(tb, wk, bk, ctxb);

    // fused attention: p += W_out @ (relu(W_v @ LN1(p) + b_v) * ctx) + b_out
    // epilogue -> LN2 stats into set B
    k_fused<256, true, false><<<dim3(32, 4, 32), 256, 0, stream>>>(
        p, meanb, rstdb, g1, b1, wbase, bvv, ctxb,
        wbase + 65536, out_b + l * Dc, p,
        nullptr, mean2, rstd2, nullptr);

    // fused FFN: p += W2 @ lrelu(W1 @ LN2(p) + b1) + b2
    // epilogue -> next LN1 (l=0: +qdot for layer 1) or LNf (l=1) into set A
    if (l == 0) {
      k_fused<512, false, true><<<dim3(32, 4, 32), 256, 0, stream>>>(
          p, mean2, rstd2, g2, b2, wbase + 131072, f1_b + l * FFc, nullptr,
          wbase + 262144, f2_b + l * Dc, p,
          wgq + 256, meanb, rstdb, qdotb);
    } else {
      k_fused<512, false, false><<<dim3(32, 4, 32), 256, 0, stream>>>(
          p, mean2, rstd2, g2, b2, wbase + 131072, f1_b + l * FFc, nullptr,
          wbase + 262144, f2_b + l * Dc, p,
          nullptr, meanb, rstdb, nullptr);
    }
  }

  k_bn2pre<<<1, 128, 0, stream>>>(bn2_g, bn2_b, bn2_m, bn2_v, bnscb, bnshb);
  // out = BN2(proj @ LNf(p)) fused with fold; LNf stats came from last FFN epilogue
  k_mm<256, 128, 256, 4096, true, S_LNF32, O_FOLDBN>
      <<<dim3(8, 4, 32), 256, 0, stream>>>(
      p, meanb, rstdb, lnf_g, lnf_b, wf_proj, nullptr, bnscb, bnshb, out);
}